// Round 1
// baseline (697.102 us; speedup 1.0000x reference)
//
#include <hip/hip_runtime.h>

#define NROWS 131072
#define DIM   64
#define KCB   1024

// ws layout (floats): ws[0] = loss accumulator; ws[256 .. 256+1023] = csq[k]

// Precompute csq[k] = sum(cb[k]^2) mimicking numpy pairwise (8-acc) order,
// and zero the loss accumulator (ws is re-poisoned to 0xAA before every call).
__global__ void vq_prep(const float* __restrict__ cb, float* __restrict__ ws) {
    int k = blockIdx.x * blockDim.x + threadIdx.x;
    if (k < KCB) {
        const float* e = cb + (k << 6);
        {
            #pragma clang fp contract(off)
            float racc[8];
            #pragma unroll
            for (int j = 0; j < 8; ++j) racc[j] = e[j] * e[j];
            #pragma unroll
            for (int t = 1; t < 8; ++t) {
                #pragma unroll
                for (int j = 0; j < 8; ++j) racc[j] += e[8 * t + j] * e[8 * t + j];
            }
            ws[256 + k] = ((racc[0] + racc[1]) + (racc[2] + racc[3]))
                        + ((racc[4] + racc[5]) + (racc[6] + racc[7]));
        }
    }
    if (k == 0) ws[0] = 0.0f;
}

// One thread per row: full argmin over 1024 codebook entries.
__global__ __launch_bounds__(256) void vq_argmin(const float* __restrict__ in,
                                                 const float* __restrict__ cb,
                                                 float* __restrict__ codes_f,
                                                 float* __restrict__ ws) {
    const int r = blockIdx.x * 256 + threadIdx.x;
    const float4* x4p = (const float4*)(in + (size_t)r * DIM);
    float x[64];
    #pragma unroll
    for (int i = 0; i < 16; ++i) {
        float4 v = x4p[i];
        x[4 * i + 0] = v.x; x[4 * i + 1] = v.y;
        x[4 * i + 2] = v.z; x[4 * i + 3] = v.w;
    }

    // A = ||x||^2, numpy pairwise 8-accumulator order, squares rounded separately
    float A;
    {
        #pragma clang fp contract(off)
        float racc[8];
        #pragma unroll
        for (int j = 0; j < 8; ++j) racc[j] = x[j] * x[j];
        #pragma unroll
        for (int t = 1; t < 8; ++t) {
            #pragma unroll
            for (int j = 0; j < 8; ++j) racc[j] += x[8 * t + j] * x[8 * t + j];
        }
        A = ((racc[0] + racc[1]) + (racc[2] + racc[3]))
          + ((racc[4] + racc[5]) + (racc[6] + racc[7]));
    }

    const float* csq = ws + 256;
    float dmin = 3.402823466e38f;
    int   kmin = 0;

    for (int k = 0; k < KCB; k += 2) {
        const float* e0 = cb + (k << 6);
        const float* e1 = e0 + 64;
        // Sequential fma chains (BLAS microkernel accumulation order),
        // two independent chains to hide dependent-fma latency.
        float m0 = 0.0f, m1 = 0.0f;
        #pragma unroll
        for (int j = 0; j < 64; ++j) {
            m0 = __builtin_fmaf(x[j], e0[j], m0);
            m1 = __builtin_fmaf(x[j], e1[j], m1);
        }
        float d0, d1;
        {
            #pragma clang fp contract(off)
            d0 = (A - 2.0f * m0) + csq[k];
            d1 = (A - 2.0f * m1) + csq[k + 1];
        }
        // strict < , ascending k => first-index tie-break (numpy argmin)
        if (d0 < dmin) { dmin = d0; kmin = k; }
        if (d1 < dmin) { dmin = d1; kmin = k + 1; }
    }

    codes_f[r] = (float)kmin;

    // loss partial: sum of d_best over rows (= sum ||x - q||^2)
    __shared__ float red[256];
    red[threadIdx.x] = dmin;
    __syncthreads();
    #pragma unroll
    for (int s = 128; s > 0; s >>= 1) {
        if (threadIdx.x < s) red[threadIdx.x] += red[threadIdx.x + s];
        __syncthreads();
    }
    if (threadIdx.x == 0) atomicAdd(ws, red[0]);
}

// Coalesced gather + straight-through write: out[i] = x + (q - x)
__global__ __launch_bounds__(256) void vq_quant(const float* __restrict__ in,
                                                const float* __restrict__ cb,
                                                const float* __restrict__ codes_f,
                                                float* __restrict__ out) {
    int t = blockIdx.x * 256 + threadIdx.x;   // one float4 per thread
    int row = t >> 4;                          // 16 threads per row
    int seg = t & 15;
    int code = (int)codes_f[row];
    const float4* q4 = (const float4*)(cb + ((size_t)code << 6));
    float4 xv = ((const float4*)in)[t];
    float4 qv = q4[seg];
    float4 st;
    {
        #pragma clang fp contract(off)
        st.x = xv.x + (qv.x - xv.x);
        st.y = xv.y + (qv.y - xv.y);
        st.z = xv.z + (qv.z - xv.z);
        st.w = xv.w + (qv.w - xv.w);
    }
    ((float4*)out)[t] = st;
}

__global__ void vq_final(const float* __restrict__ ws, float* __restrict__ loss_out) {
    // loss = codebook_loss + BETA*commitment = 1.25 * mean((x-q)^2)
    loss_out[0] = 1.25f * ws[0] / 8388608.0f;
}

extern "C" void kernel_launch(void* const* d_in, const int* in_sizes, int n_in,
                              void* d_out, int out_size, void* d_ws, size_t ws_size,
                              hipStream_t stream) {
    const float* in = (const float*)d_in[0];   // (32,4096,64) fp32
    const float* cb = (const float*)d_in[1];   // (1024,64)    fp32
    float* out     = (float*)d_out;
    float* codes_f = out + 8388608;
    float* loss_p  = out + 8519680;
    float* ws      = (float*)d_ws;

    vq_prep  <<<4,    256, 0, stream>>>(cb, ws);
    vq_argmin<<<512,  256, 0, stream>>>(in, cb, codes_f, ws);
    vq_quant <<<8192, 256, 0, stream>>>(in, cb, codes_f, out);
    vq_final <<<1,    1,   0, stream>>>(ws, loss_p);
}